// Round 6
// baseline (867.931 us; speedup 1.0000x reference)
//
#include <hip/hip_runtime.h>
#include <hip/hip_bf16.h>

// Problem constants
#define MROWS 4096
#define TSTEPS 100
#define EMB 64
#define HID 128
#define GATES 512        // 4*HID
#define KTOT 192         // EMB + HID
#define ROWS_PB 16       // rows per block (one direction)
#define SROW 200         // padded A-panel row stride in f16 elems (400B, 16B aligned)

typedef _Float16 half8 __attribute__((ext_vector_type(8)));
typedef _Float16 half4v __attribute__((ext_vector_type(4)));
typedef float f32x4 __attribute__((ext_vector_type(4)));

#define LOG2E  1.44269504f
#define LOG2E2 2.88539008f

__device__ __forceinline__ float rcpf(float x) { return __builtin_amdgcn_rcpf(x); }
__device__ __forceinline__ float ex2(float x) { return __builtin_amdgcn_exp2f(x); }

// ---------------------------------------------------------------------------
// Kernel 1: scores = softmax(relu(obs @ attn_W + attn_b), axis=1)  (256 x 100)
// EXACT round-1 code (proven).
// ---------------------------------------------------------------------------
__global__ void attn_scores_kernel(const float* __restrict__ obs,
                                   const float* __restrict__ attn_W,
                                   const float* __restrict__ attn_b,
                                   float* __restrict__ scores) {
    const int row = blockIdx.x;      // 256 rows
    const int tid = threadIdx.x;     // 128 threads
    __shared__ float obs_s[128];
    __shared__ float red[128];

    obs_s[tid] = obs[row * 128 + tid];
    __syncthreads();

    float s = -1e30f;
    if (tid < 100) {
        float a = attn_b[tid];
        #pragma unroll 4
        for (int k = 0; k < 128; k++) a += obs_s[k] * attn_W[k * 100 + tid];
        s = fmaxf(a, 0.f);
    }
    red[tid] = s;
    __syncthreads();
    for (int off = 64; off > 0; off >>= 1) {
        if (tid < off) red[tid] = fmaxf(red[tid], red[tid + off]);
        __syncthreads();
    }
    const float m = red[0];
    __syncthreads();
    const float e = (tid < 100) ? __expf(s - m) : 0.f;
    red[tid] = e;
    __syncthreads();
    for (int off = 64; off > 0; off >>= 1) {
        if (tid < off) red[tid] += red[tid + off];
        __syncthreads();
    }
    const float inv = __fdividef(1.f, red[0]);
    if (tid < 100) scores[row * 100 + tid] = e * inv;
}

// ---------------------------------------------------------------------------
// Kernel 1b: encWT[c][k] = (f16) enc_W[k][c]   (1024x128 -> 128x1024 f16)
// (round-5, proven)
// ---------------------------------------------------------------------------
__global__ void encw_prep_kernel(const float* __restrict__ enc_W,
                                 _Float16* __restrict__ encWT) {
    __shared__ float tile[64][129];
    const int k0 = blockIdx.x * 64;
    const int tid = threadIdx.x;     // 256
    #pragma unroll
    for (int i = 0; i < 32; i++) {
        const int idx = tid + i * 256;
        const int rr = idx >> 7, cc = idx & 127;
        tile[rr][cc] = enc_W[(k0 + rr) * 128 + cc];
    }
    __syncthreads();
    const int c = tid >> 1, hh = tid & 1;
    #pragma unroll
    for (int j = 0; j < 32; j++) {
        encWT[c * 1024 + k0 + hh * 32 + j] = (_Float16)tile[hh * 32 + j][c];
    }
}

// ---------------------------------------------------------------------------
// Kernel 2: persistent bidirectional LSTM, fused embedding + online pooling.
// 512 blocks (256 fwd + 256 bwd) x 512 thr, 16 rows/block -> 2 blocks/CU.
// Weights register-resident in MFMA B layout with exp2 scales folded;
// cell update via v_exp/v_rcp (no IEEE div).
// ---------------------------------------------------------------------------
__launch_bounds__(512, 4)
__global__ void lstm_kernel(const float* __restrict__ lane_features,
                            const float* __restrict__ embed_W,
                            const float* __restrict__ embed_b,
                            const float* __restrict__ Wih_f,
                            const float* __restrict__ Whh_f,
                            const float* __restrict__ b_f,
                            const float* __restrict__ Wih_b,
                            const float* __restrict__ Whh_b,
                            const float* __restrict__ b_b,
                            const float* __restrict__ h0,
                            const float* __restrict__ c0,
                            const int*   __restrict__ mask,
                            const float* __restrict__ scores,
                            float* __restrict__ out_feat) {
    const int blk = blockIdx.x;
    const int d = blk >> 8;                     // 0 = fwd, 1 = bwd
    const int rowbase = (blk & 255) * ROWS_PB;
    const int tid = threadIdx.x;
    const int wave = tid >> 6;
    const int lane = tid & 63;
    const int lane16 = lane & 15;
    const int quad = lane >> 4;

    const float* Wih = d ? Wih_b : Wih_f;
    const float* Whh = d ? Whh_b : Whh_f;
    const float* bia = d ? b_b : b_f;

    __shared__ __attribute__((aligned(16))) _Float16 panel[2][ROWS_PB][SROW];
    __shared__ float att_s[ROWS_PB][100];

    // ---- Per-thread embed weights (2 columns: cc, cc+1) ----
    const int erow = tid >> 5;                  // 0..15: row this thread embeds
    const int cc = (tid & 31) * 2;
    float ew_r[4][2], eb_r[2];
    #pragma unroll
    for (int j = 0; j < 4; j++) {
        ew_r[j][0] = embed_W[j * EMB + cc];
        ew_r[j][1] = embed_W[j * EMB + cc + 1];
    }
    eb_r[0] = embed_b[cc];
    eb_r[1] = embed_b[cc + 1];

    // ---- att gather: att_s[r][t] = scores[mask[r]*100 + t] (one time) ----
    {
        const int r = tid >> 5, tcol = tid & 31;
        const int mr = mask[rowbase + r];
        for (int t = tcol; t < 100; t += 32) att_s[r][t] = scores[mr * 100 + t];
    }

    // ---- Preload B fragments (MFMA B layout), exp2 scales folded ----
    const int unitg = wave * 16 + lane16;
    half8 Bf[24];   // [ct][ki] -> 96 VGPRs
    #pragma unroll
    for (int ct = 0; ct < 4; ct++) {
        const float scale = (ct == 2) ? LOG2E2 : LOG2E;
        const int col = ct * 128 + unitg;
        #pragma unroll
        for (int ki = 0; ki < 6; ki++) {
            half8 b;
            #pragma unroll
            for (int j = 0; j < 8; j++) {
                const int kk = ki * 32 + quad * 8 + j;
                const float w = (kk < EMB) ? Wih[kk * GATES + col]
                                           : Whh[(kk - EMB) * GATES + col];
                b[j] = (_Float16)(w * scale);
            }
            Bf[ct * 6 + ki] = b;
        }
    }
    float bgate[4];
    #pragma unroll
    for (int ct = 0; ct < 4; ct++)
        bgate[ct] = bia[ct * 128 + unitg] * ((ct == 2) ? LOG2E2 : LOG2E);

    // ---- Per-lane state: 4 (row,unit) pairs in C-layout ----
    float cst[4], mx[4], as[4], h0s[4], hl[4];
    const float cinit = c0[d * 128 + unitg];
    #pragma unroll
    for (int p = 0; p < 4; p++) {
        cst[p] = cinit; mx[p] = -1e30f; as[p] = 0.f; h0s[p] = 0.f; hl[p] = 0.f;
    }

    // ---- Init panel[0]: h part (16*128 over 512 threads) ----
    for (int idx = tid; idx < ROWS_PB * HID; idx += 512) {
        const int r = idx >> 7, u = idx & 127;
        panel[0][r][EMB + u] = (_Float16)h0[d * 128 + u];
    }

    // ---- Init panel[0]: x for first step ----
    {
        const int t0 = d ? (TSTEPS - 1) : 0;
        const float4 fv = *(const float4*)(lane_features + (long)(rowbase + erow) * 600 + 200 + 4 * t0);
        #pragma unroll
        for (int jj = 0; jj < 2; jj++) {
            float e = eb_r[jj] + fv.x * ew_r[0][jj] + fv.y * ew_r[1][jj]
                               + fv.z * ew_r[2][jj] + fv.w * ew_r[3][jj];
            panel[0][erow][cc + jj] = (_Float16)fmaxf(e, 0.f);
        }
    }
    __syncthreads();

    // ================= main recurrence =================
    for (int s = 0; s < TSTEPS; s++) {
        const int p = s & 1;
        const int t = d ? (TSTEPS - 1 - s) : s;

        // prefetch next x features (VMEM latency overlaps MFMA below)
        float4 fv;
        if (s < TSTEPS - 1) {
            const int tn = d ? (TSTEPS - 2 - s) : (s + 1);
            fv = *(const float4*)(lane_features + (long)(rowbase + erow) * 600 + 200 + 4 * tn);
        }

        // attention weights (LDS broadcast reads)
        float aw[4];
        #pragma unroll
        for (int pp = 0; pp < 4; pp++) aw[pp] = att_s[quad * 4 + pp][t];

        // accumulators pre-seeded with folded biases
        f32x4 acc[4];
        #pragma unroll
        for (int ct = 0; ct < 4; ct++) {
            const float bg = bgate[ct];
            acc[ct] = (f32x4){bg, bg, bg, bg};
        }

        #pragma unroll
        for (int ki = 0; ki < 6; ki++) {
            const half8 a0 = *(const half8*)&panel[p][lane16][ki * 32 + quad * 8];
            #pragma unroll
            for (int ct = 0; ct < 4; ct++) {
                acc[ct] = __builtin_amdgcn_mfma_f32_16x16x32_f16(a0, Bf[ct * 6 + ki], acc[ct], 0, 0, 0);
            }
        }

        // ---- cell update + online pooling (exp2-folded gates) ----
        // i,f,o pre-scaled by log2e; g by 2*log2e
        #pragma unroll
        for (int r = 0; r < 4; r++) {
            const int row_local = quad * 4 + r;
            const float gi = acc[0][r];
            const float gf = acc[1][r];
            const float gg = fminf(acc[2][r], 80.f);
            const float go = acc[3][r];
            const float Ei = ex2(-gi);
            const float Ef = ex2(-gf);
            const float Eg = ex2(gg);
            const float Eo = ex2(-go);
            const float sf = rcpf(1.f + Ef);                       // sigmoid(f)
            const float r1 = rcpf((1.f + Ei) * (Eg + 1.f));
            const float cn = sf * cst[r] + (Eg - 1.f) * r1;        // + sig(i)*tanh(g)
            const float Ec = ex2(fminf(cn * LOG2E2, 80.f));
            const float r2 = rcpf((1.f + Eo) * (Ec + 1.f));
            const float h = (Ec - 1.f) * r2;                       // sig(o)*tanh(c)
            cst[r] = cn;
            hl[r] = h;
            mx[r] = fmaxf(mx[r], h);
            as[r] = fmaf(aw[r], h, as[r]);
            panel[1 - p][row_local][EMB + unitg] = (_Float16)h;
        }
        if (s == 0) {
            #pragma unroll
            for (int pp = 0; pp < 4; pp++) h0s[pp] = hl[pp];
        }

        // ---- embed prefetched x into the other buffer ----
        if (s < TSTEPS - 1) {
            float e0 = eb_r[0] + fv.x * ew_r[0][0] + fv.y * ew_r[1][0] + fv.z * ew_r[2][0] + fv.w * ew_r[3][0];
            float e1 = eb_r[1] + fv.x * ew_r[0][1] + fv.y * ew_r[1][1] + fv.z * ew_r[2][1] + fv.w * ew_r[3][1];
            panel[1 - p][erow][cc]     = (_Float16)fmaxf(e0, 0.f);
            panel[1 - p][erow][cc + 1] = (_Float16)fmaxf(e1, 0.f);
        }
        __syncthreads();
    }

    // ---- pooled features: [front | back | max | attn], f32 (round-5 path) ----
    #pragma unroll
    for (int pp = 0; pp < 4; pp++) {
        const int row_local = quad * 4 + pp;
        const long ro = (long)(rowbase + row_local) * 1024;
        const int cu = d * 128 + unitg;
        const float fr = d ? hl[pp] : h0s[pp];
        const float bk = d ? h0s[pp] : hl[pp];
        out_feat[ro + cu]       = fr;
        out_feat[ro + 256 + cu] = bk;
        out_feat[ro + 512 + cu] = mx[pp];
        out_feat[ro + 768 + cu] = as[pp];
    }
}

// ---------------------------------------------------------------------------
// Kernel 3: out = relu(out_feat(4096x1024,f32) @ enc_W(1024x128) + enc_b)
// MFMA f16 with in-kernel f32->f16 staging (round-5, proven).
// ---------------------------------------------------------------------------
__launch_bounds__(256, 2)
__global__ void enc_kernel(const float* __restrict__ out_feat,
                           const _Float16* __restrict__ encWT,
                           const float* __restrict__ enc_b,
                           float* __restrict__ out) {
    const int rb = blockIdx.x * 16;
    const int tid = threadIdx.x;
    const int wave = tid >> 6;
    const int lane = tid & 63;
    const int lane16 = lane & 15;
    const int quad = lane >> 4;

    __shared__ __attribute__((aligned(16))) _Float16 A16[16][1032];

    // stage 16 rows x 1024 of A: load f32, convert to f16
    #pragma unroll
    for (int i = 0; i < 16; i++) {
        const int u = tid + i * 256;            // 0..4095, units of float4
        const int row = u >> 8, kc = u & 255;
        const float4 v = *(const float4*)(out_feat + (long)(rb + row) * 1024 + kc * 4);
        half4v hv;
        hv[0] = (_Float16)v.x; hv[1] = (_Float16)v.y;
        hv[2] = (_Float16)v.z; hv[3] = (_Float16)v.w;
        *(half4v*)&A16[row][kc * 4] = hv;
    }
    __syncthreads();

    const int col0 = wave * 32 + lane16;
    f32x4 acc0 = {0.f, 0.f, 0.f, 0.f}, acc1 = {0.f, 0.f, 0.f, 0.f};

    #pragma unroll 4
    for (int it = 0; it < 32; it++) {
        const half8 a  = *(const half8*)&A16[lane16][it * 32 + quad * 8];
        const half8 b0 = *(const half8*)(encWT + (long)col0 * 1024 + it * 32 + quad * 8);
        const half8 b1 = *(const half8*)(encWT + (long)(col0 + 16) * 1024 + it * 32 + quad * 8);
        acc0 = __builtin_amdgcn_mfma_f32_16x16x32_f16(a, b0, acc0, 0, 0, 0);
        acc1 = __builtin_amdgcn_mfma_f32_16x16x32_f16(a, b1, acc1, 0, 0, 0);
    }

    const float bb0 = enc_b[col0], bb1 = enc_b[col0 + 16];
    #pragma unroll
    for (int r = 0; r < 4; r++) {
        const int row = rb + quad * 4 + r;
        out[(long)row * 128 + col0]      = fmaxf(acc0[r] + bb0, 0.f);
        out[(long)row * 128 + col0 + 16] = fmaxf(acc1[r] + bb1, 0.f);
    }
}

// ---------------------------------------------------------------------------
extern "C" void kernel_launch(void* const* d_in, const int* in_sizes, int n_in,
                              void* d_out, int out_size, void* d_ws, size_t ws_size,
                              hipStream_t stream) {
    const float* lane_features = (const float*)d_in[0];
    const float* obs_encoding  = (const float*)d_in[1];
    const float* embed_W = (const float*)d_in[2];
    const float* embed_b = (const float*)d_in[3];
    const float* attn_W  = (const float*)d_in[4];
    const float* attn_b  = (const float*)d_in[5];
    const float* Wih_f   = (const float*)d_in[6];
    const float* Whh_f   = (const float*)d_in[7];
    const float* b_f     = (const float*)d_in[8];
    const float* Wih_b   = (const float*)d_in[9];
    const float* Whh_b   = (const float*)d_in[10];
    const float* b_b     = (const float*)d_in[11];
    const float* h0      = (const float*)d_in[12];
    const float* c0      = (const float*)d_in[13];
    const float* enc_W   = (const float*)d_in[14];
    const float* enc_b   = (const float*)d_in[15];
    const int*   mask    = (const int*)d_in[16];

    float*     scores   = (float*)d_ws;                            // 256*100 f32
    _Float16*  encWT    = (_Float16*)((char*)d_ws + (128 << 10));  // 128*1024 f16 (256 KB)
    float*     out_feat = (float*)((char*)d_ws + (384 << 10));     // 4096*1024 f32 (16 MB)
    float*     out      = (float*)d_out;                           // 4096*128 f32

    attn_scores_kernel<<<256, 128, 0, stream>>>(obs_encoding, attn_W, attn_b, scores);
    encw_prep_kernel<<<16, 256, 0, stream>>>(enc_W, encWT);
    lstm_kernel<<<512, 512, 0, stream>>>(lane_features, embed_W, embed_b,
                                         Wih_f, Whh_f, b_f, Wih_b, Whh_b, b_b,
                                         h0, c0, mask, scores, out_feat);
    enc_kernel<<<256, 256, 0, stream>>>(out_feat, encWT, enc_b, out);
}

// Round 7
// 305.661 us; speedup vs baseline: 2.8395x; 2.8395x over previous
//
#include <hip/hip_runtime.h>
#include <hip/hip_bf16.h>

// Problem constants
#define MROWS 4096
#define TSTEPS 100
#define EMB 64
#define HID 128
#define GATES 512        // 4*HID
#define KTOT 192         // EMB + HID
#define ROWS_PB 32       // rows per block (one direction)
#define SROW 200         // padded A-panel row stride in f16 elems (400B, 16B aligned)

typedef _Float16 half8 __attribute__((ext_vector_type(8)));
typedef _Float16 half4v __attribute__((ext_vector_type(4)));
typedef float f32x4 __attribute__((ext_vector_type(4)));

#define LOG2E  1.44269504f
#define LOG2E2 2.88539008f

__device__ __forceinline__ float rcpf(float x) { return __builtin_amdgcn_rcpf(x); }
__device__ __forceinline__ float ex2(float x) { return __builtin_amdgcn_exp2f(x); }

// ---------------------------------------------------------------------------
// Kernel 1: scores = softmax(relu(obs @ attn_W + attn_b), axis=1)  (256 x 100)
// EXACT round-1 code (proven).
// ---------------------------------------------------------------------------
__global__ void attn_scores_kernel(const float* __restrict__ obs,
                                   const float* __restrict__ attn_W,
                                   const float* __restrict__ attn_b,
                                   float* __restrict__ scores) {
    const int row = blockIdx.x;      // 256 rows
    const int tid = threadIdx.x;     // 128 threads
    __shared__ float obs_s[128];
    __shared__ float red[128];

    obs_s[tid] = obs[row * 128 + tid];
    __syncthreads();

    float s = -1e30f;
    if (tid < 100) {
        float a = attn_b[tid];
        #pragma unroll 4
        for (int k = 0; k < 128; k++) a += obs_s[k] * attn_W[k * 100 + tid];
        s = fmaxf(a, 0.f);
    }
    red[tid] = s;
    __syncthreads();
    for (int off = 64; off > 0; off >>= 1) {
        if (tid < off) red[tid] = fmaxf(red[tid], red[tid + off]);
        __syncthreads();
    }
    const float m = red[0];
    __syncthreads();
    const float e = (tid < 100) ? __expf(s - m) : 0.f;
    red[tid] = e;
    __syncthreads();
    for (int off = 64; off > 0; off >>= 1) {
        if (tid < off) red[tid] += red[tid + off];
        __syncthreads();
    }
    const float inv = __fdividef(1.f, red[0]);
    if (tid < 100) scores[row * 100 + tid] = e * inv;
}

// ---------------------------------------------------------------------------
// Kernel 1b: encWT[c][k] = (f16) enc_W[k][c]   (1024x128 -> 128x1024 f16)
// (round-5, proven)
// ---------------------------------------------------------------------------
__global__ void encw_prep_kernel(const float* __restrict__ enc_W,
                                 _Float16* __restrict__ encWT) {
    __shared__ float tile[64][129];
    const int k0 = blockIdx.x * 64;
    const int tid = threadIdx.x;     // 256
    #pragma unroll
    for (int i = 0; i < 32; i++) {
        const int idx = tid + i * 256;
        const int rr = idx >> 7, cc = idx & 127;
        tile[rr][cc] = enc_W[(k0 + rr) * 128 + cc];
    }
    __syncthreads();
    const int c = tid >> 1, hh = tid & 1;
    #pragma unroll
    for (int j = 0; j < 32; j++) {
        encWT[c * 1024 + k0 + hh * 32 + j] = (_Float16)tile[hh * 32 + j][c];
    }
}

// ---------------------------------------------------------------------------
// Kernel 2: persistent bidirectional LSTM (round-5 structure, proven 404us)
// + exp2-folded cell math (proven correct in round 6).
// 256 blocks x 512 thr, 32 rows/block, 1 block/CU, weights in VGPRs.
// NOTE: launch_bounds(512,2) = 256-VGPR budget. (512,4) forces spill of the
// 96-VGPR B fragments -> 2.5 GB scratch traffic (round-6 regression).
// ---------------------------------------------------------------------------
__launch_bounds__(512, 2)
__global__ void lstm_kernel(const float* __restrict__ lane_features,
                            const float* __restrict__ embed_W,
                            const float* __restrict__ embed_b,
                            const float* __restrict__ Wih_f,
                            const float* __restrict__ Whh_f,
                            const float* __restrict__ b_f,
                            const float* __restrict__ Wih_b,
                            const float* __restrict__ Whh_b,
                            const float* __restrict__ b_b,
                            const float* __restrict__ h0,
                            const float* __restrict__ c0,
                            const int*   __restrict__ mask,
                            const float* __restrict__ scores,
                            float* __restrict__ out_feat) {
    const int blk = blockIdx.x;
    const int d = blk >> 7;                     // 0 = fwd, 1 = bwd
    const int rowbase = (blk & 127) * ROWS_PB;
    const int tid = threadIdx.x;
    const int wave = tid >> 6;
    const int lane = tid & 63;
    const int lane16 = lane & 15;
    const int quad = lane >> 4;

    const float* Wih = d ? Wih_b : Wih_f;
    const float* Whh = d ? Whh_b : Whh_f;
    const float* bia = d ? b_b : b_f;

    __shared__ __attribute__((aligned(16))) _Float16 panel[2][ROWS_PB][SROW];
    __shared__ float att_s[ROWS_PB][100];

    // ---- Per-thread embed weights (columns cc..cc+3) ----
    const int erow = tid >> 4;                  // row this thread embeds
    const int cc = (tid & 15) * 4;
    float ew_r[4][4], eb_r[4];
    #pragma unroll
    for (int j = 0; j < 4; j++) {
        #pragma unroll
        for (int jj = 0; jj < 4; jj++) ew_r[j][jj] = embed_W[j * EMB + cc + jj];
    }
    #pragma unroll
    for (int jj = 0; jj < 4; jj++) eb_r[jj] = embed_b[cc + jj];

    // ---- att gather: att_s[r][t] = scores[mask[r]*100 + t] (one time) ----
    {
        const int r = tid >> 4, tcol = tid & 15;
        const int mr = mask[rowbase + r];
        for (int t = tcol; t < 100; t += 16) att_s[r][t] = scores[mr * 100 + t];
    }

    // ---- Preload B fragments (MFMA B layout), exp2 scales folded ----
    const int unitg = wave * 16 + lane16;
    half8 Bf[24];   // [ct][ki] -> 96 VGPRs
    #pragma unroll
    for (int ct = 0; ct < 4; ct++) {
        const float scale = (ct == 2) ? LOG2E2 : LOG2E;
        const int col = ct * 128 + unitg;
        #pragma unroll
        for (int ki = 0; ki < 6; ki++) {
            half8 b;
            #pragma unroll
            for (int j = 0; j < 8; j++) {
                const int kk = ki * 32 + quad * 8 + j;
                const float w = (kk < EMB) ? Wih[kk * GATES + col]
                                           : Whh[(kk - EMB) * GATES + col];
                b[j] = (_Float16)(w * scale);
            }
            Bf[ct * 6 + ki] = b;
        }
    }
    float bgate[4];
    #pragma unroll
    for (int ct = 0; ct < 4; ct++)
        bgate[ct] = bia[ct * 128 + unitg] * ((ct == 2) ? LOG2E2 : LOG2E);

    // ---- Per-lane state: 8 (row,unit) pairs in C-layout ----
    float cst[8], mx[8], as[8], h0s[8], hl[8];
    const float cinit = c0[d * 128 + unitg];
    #pragma unroll
    for (int p = 0; p < 8; p++) {
        cst[p] = cinit; mx[p] = -1e30f; as[p] = 0.f; h0s[p] = 0.f; hl[p] = 0.f;
    }

    // ---- Init panel[0]: h part ----
    for (int idx = tid; idx < ROWS_PB * HID; idx += 512) {
        const int r = idx >> 7, u = idx & 127;
        panel[0][r][EMB + u] = (_Float16)h0[d * 128 + u];
    }

    // ---- Init panel[0]: x for first step ----
    {
        const int t0 = d ? (TSTEPS - 1) : 0;
        const float4 fv = *(const float4*)(lane_features + (long)(rowbase + erow) * 600 + 200 + 4 * t0);
        #pragma unroll
        for (int jj = 0; jj < 4; jj++) {
            float e = eb_r[jj] + fv.x * ew_r[0][jj] + fv.y * ew_r[1][jj]
                               + fv.z * ew_r[2][jj] + fv.w * ew_r[3][jj];
            panel[0][erow][cc + jj] = (_Float16)fmaxf(e, 0.f);
        }
    }
    __syncthreads();

    // ================= main recurrence =================
    for (int s = 0; s < TSTEPS; s++) {
        const int p = s & 1;
        const int t = d ? (TSTEPS - 1 - s) : s;

        // prefetch next x features (VMEM latency overlaps MFMA below)
        float4 fv;
        if (s < TSTEPS - 1) {
            const int tn = d ? (TSTEPS - 2 - s) : (s + 1);
            fv = *(const float4*)(lane_features + (long)(rowbase + erow) * 600 + 200 + 4 * tn);
        }

        // attention weights (LDS broadcast reads)
        float aw[8];
        #pragma unroll
        for (int pp = 0; pp < 8; pp++) {
            const int row_local = (pp >> 2) * 16 + quad * 4 + (pp & 3);
            aw[pp] = att_s[row_local][t];
        }

        // accumulators pre-seeded with folded biases
        f32x4 acc[2][4];
        #pragma unroll
        for (int rt = 0; rt < 2; rt++)
            #pragma unroll
            for (int ct = 0; ct < 4; ct++) {
                const float bg = bgate[ct];
                acc[rt][ct] = (f32x4){bg, bg, bg, bg};
            }

        #pragma unroll
        for (int ki = 0; ki < 6; ki++) {
            const half8 a0 = *(const half8*)&panel[p][lane16][ki * 32 + quad * 8];
            const half8 a1 = *(const half8*)&panel[p][16 + lane16][ki * 32 + quad * 8];
            #pragma unroll
            for (int ct = 0; ct < 4; ct++) {
                acc[0][ct] = __builtin_amdgcn_mfma_f32_16x16x32_f16(a0, Bf[ct * 6 + ki], acc[0][ct], 0, 0, 0);
                acc[1][ct] = __builtin_amdgcn_mfma_f32_16x16x32_f16(a1, Bf[ct * 6 + ki], acc[1][ct], 0, 0, 0);
            }
        }

        // ---- cell update + online pooling (exp2-folded gates, proven r6) ----
        // i,f,o pre-scaled by log2e; g by 2*log2e
        #pragma unroll
        for (int rt = 0; rt < 2; rt++) {
            #pragma unroll
            for (int r = 0; r < 4; r++) {
                const int pp = rt * 4 + r;
                const int row_local = rt * 16 + quad * 4 + r;
                const float gi = acc[rt][0][r];
                const float gf = acc[rt][1][r];
                const float gg = fminf(acc[rt][2][r], 80.f);
                const float go = acc[rt][3][r];
                const float Ei = ex2(-gi);
                const float Ef = ex2(-gf);
                const float Eg = ex2(gg);
                const float Eo = ex2(-go);
                const float sf = rcpf(1.f + Ef);                       // sigmoid(f)
                const float r1 = rcpf((1.f + Ei) * (Eg + 1.f));
                const float cn = sf * cst[pp] + (Eg - 1.f) * r1;       // + sig(i)*tanh(g)
                const float Ec = ex2(fminf(cn * LOG2E2, 80.f));
                const float r2 = rcpf((1.f + Eo) * (Ec + 1.f));
                const float h = (Ec - 1.f) * r2;                       // sig(o)*tanh(c)
                cst[pp] = cn;
                hl[pp] = h;
                mx[pp] = fmaxf(mx[pp], h);
                as[pp] = fmaf(aw[pp], h, as[pp]);
                panel[1 - p][row_local][EMB + unitg] = (_Float16)h;
            }
        }
        if (s == 0) {
            #pragma unroll
            for (int pp = 0; pp < 8; pp++) h0s[pp] = hl[pp];
        }

        // ---- embed prefetched x into the other buffer ----
        if (s < TSTEPS - 1) {
            float e0 = eb_r[0] + fv.x * ew_r[0][0] + fv.y * ew_r[1][0] + fv.z * ew_r[2][0] + fv.w * ew_r[3][0];
            float e1 = eb_r[1] + fv.x * ew_r[0][1] + fv.y * ew_r[1][1] + fv.z * ew_r[2][1] + fv.w * ew_r[3][1];
            float e2 = eb_r[2] + fv.x * ew_r[0][2] + fv.y * ew_r[1][2] + fv.z * ew_r[2][2] + fv.w * ew_r[3][2];
            float e3 = eb_r[3] + fv.x * ew_r[0][3] + fv.y * ew_r[1][3] + fv.z * ew_r[2][3] + fv.w * ew_r[3][3];
            panel[1 - p][erow][cc]     = (_Float16)fmaxf(e0, 0.f);
            panel[1 - p][erow][cc + 1] = (_Float16)fmaxf(e1, 0.f);
            panel[1 - p][erow][cc + 2] = (_Float16)fmaxf(e2, 0.f);
            panel[1 - p][erow][cc + 3] = (_Float16)fmaxf(e3, 0.f);
        }
        __syncthreads();
    }

    // ---- pooled features: [front | back | max | attn], f32 ----
    #pragma unroll
    for (int pp = 0; pp < 8; pp++) {
        const int row_local = (pp >> 2) * 16 + quad * 4 + (pp & 3);
        const long ro = (long)(rowbase + row_local) * 1024;
        const int cu = d * 128 + unitg;
        const float fr = d ? hl[pp] : h0s[pp];
        const float bk = d ? h0s[pp] : hl[pp];
        out_feat[ro + cu]       = fr;
        out_feat[ro + 256 + cu] = bk;
        out_feat[ro + 512 + cu] = mx[pp];
        out_feat[ro + 768 + cu] = as[pp];
    }
}

// ---------------------------------------------------------------------------
// Kernel 3: out = relu(out_feat(4096x1024,f32) @ enc_W(1024x128) + enc_b)
// MFMA f16 with in-kernel f32->f16 staging (round-5, proven).
// ---------------------------------------------------------------------------
__launch_bounds__(256, 2)
__global__ void enc_kernel(const float* __restrict__ out_feat,
                           const _Float16* __restrict__ encWT,
                           const float* __restrict__ enc_b,
                           float* __restrict__ out) {
    const int rb = blockIdx.x * 16;
    const int tid = threadIdx.x;
    const int wave = tid >> 6;
    const int lane = tid & 63;
    const int lane16 = lane & 15;
    const int quad = lane >> 4;

    __shared__ __attribute__((aligned(16))) _Float16 A16[16][1032];

    // stage 16 rows x 1024 of A: load f32, convert to f16
    #pragma unroll
    for (int i = 0; i < 16; i++) {
        const int u = tid + i * 256;            // 0..4095, units of float4
        const int row = u >> 8, kc = u & 255;
        const float4 v = *(const float4*)(out_feat + (long)(rb + row) * 1024 + kc * 4);
        half4v hv;
        hv[0] = (_Float16)v.x; hv[1] = (_Float16)v.y;
        hv[2] = (_Float16)v.z; hv[3] = (_Float16)v.w;
        *(half4v*)&A16[row][kc * 4] = hv;
    }
    __syncthreads();

    const int col0 = wave * 32 + lane16;
    f32x4 acc0 = {0.f, 0.f, 0.f, 0.f}, acc1 = {0.f, 0.f, 0.f, 0.f};

    #pragma unroll 4
    for (int it = 0; it < 32; it++) {
        const half8 a  = *(const half8*)&A16[lane16][it * 32 + quad * 8];
        const half8 b0 = *(const half8*)(encWT + (long)col0 * 1024 + it * 32 + quad * 8);
        const half8 b1 = *(const half8*)(encWT + (long)(col0 + 16) * 1024 + it * 32 + quad * 8);
        acc0 = __builtin_amdgcn_mfma_f32_16x16x32_f16(a, b0, acc0, 0, 0, 0);
        acc1 = __builtin_amdgcn_mfma_f32_16x16x32_f16(a, b1, acc1, 0, 0, 0);
    }

    const float bb0 = enc_b[col0], bb1 = enc_b[col0 + 16];
    #pragma unroll
    for (int r = 0; r < 4; r++) {
        const int row = rb + quad * 4 + r;
        out[(long)row * 128 + col0]      = fmaxf(acc0[r] + bb0, 0.f);
        out[(long)row * 128 + col0 + 16] = fmaxf(acc1[r] + bb1, 0.f);
    }
}

// ---------------------------------------------------------------------------
extern "C" void kernel_launch(void* const* d_in, const int* in_sizes, int n_in,
                              void* d_out, int out_size, void* d_ws, size_t ws_size,
                              hipStream_t stream) {
    const float* lane_features = (const float*)d_in[0];
    const float* obs_encoding  = (const float*)d_in[1];
    const float* embed_W = (const float*)d_in[2];
    const float* embed_b = (const float*)d_in[3];
    const float* attn_W  = (const float*)d_in[4];
    const float* attn_b  = (const float*)d_in[5];
    const float* Wih_f   = (const float*)d_in[6];
    const float* Whh_f   = (const float*)d_in[7];
    const float* b_f     = (const float*)d_in[8];
    const float* Wih_b   = (const float*)d_in[9];
    const float* Whh_b   = (const float*)d_in[10];
    const float* b_b     = (const float*)d_in[11];
    const float* h0      = (const float*)d_in[12];
    const float* c0      = (const float*)d_in[13];
    const float* enc_W   = (const float*)d_in[14];
    const float* enc_b   = (const float*)d_in[15];
    const int*   mask    = (const int*)d_in[16];

    float*     scores   = (float*)d_ws;                            // 256*100 f32
    _Float16*  encWT    = (_Float16*)((char*)d_ws + (128 << 10));  // 128*1024 f16 (256 KB)
    float*     out_feat = (float*)((char*)d_ws + (384 << 10));     // 4096*1024 f32 (16 MB)
    float*     out      = (float*)d_out;                           // 4096*128 f32

    attn_scores_kernel<<<256, 128, 0, stream>>>(obs_encoding, attn_W, attn_b, scores);
    encw_prep_kernel<<<16, 256, 0, stream>>>(enc_W, encWT);
    lstm_kernel<<<256, 512, 0, stream>>>(lane_features, embed_W, embed_b,
                                         Wih_f, Whh_f, b_f, Wih_b, Whh_b, b_b,
                                         h0, c0, mask, scores, out_feat);
    enc_kernel<<<256, 256, 0, stream>>>(out_feat, encWT, enc_b, out);
}

// Round 8
// 299.588 us; speedup vs baseline: 2.8971x; 1.0203x over previous
//
#include <hip/hip_runtime.h>
#include <hip/hip_bf16.h>

// Problem constants
#define MROWS 4096
#define TSTEPS 100
#define EMB 64
#define HID 128
#define GATES 512        // 4*HID
#define KTOT 192         // EMB + HID
#define ROWS_PB 32       // rows per block (one direction)
#define SROW 200         // padded A-panel row stride in f16 elems (400B, 16B aligned)

typedef _Float16 half8 __attribute__((ext_vector_type(8)));
typedef float f32x4 __attribute__((ext_vector_type(4)));

#define LOG2E  1.44269504f
#define LOG2E2 2.88539008f

__device__ __forceinline__ float rcpf(float x) { return __builtin_amdgcn_rcpf(x); }
__device__ __forceinline__ float ex2(float x) { return __builtin_amdgcn_exp2f(x); }

// ---------------------------------------------------------------------------
// Kernel 1 (merged prep):
//  blocks 0..255:  scores = softmax(relu(obs @ attn_W + attn_b)) (round-1 math)
//  blocks 256..271: enc_W (1024x128 f32) -> MFMA-B-fragment-ordered f16 table
//     frag[((tile*32 + it)*64 + lane)*8 + j] = enc_W[(it*32+(lane>>4)*8+j)*128
//                                                     + tile*16 + (lane&15)]
//  (same element mapping the proven enc_kernel used, stored coalesced)
// ---------------------------------------------------------------------------
__global__ void prep_kernel(const float* __restrict__ obs,
                            const float* __restrict__ attn_W,
                            const float* __restrict__ attn_b,
                            float* __restrict__ scores,
                            const float* __restrict__ enc_W,
                            _Float16* __restrict__ frag) {
    const int tid = threadIdx.x;     // 256
    if (blockIdx.x < 256) {
        const int row = blockIdx.x;
        __shared__ float obs_s[128];
        __shared__ float red[128];

        if (tid < 128) obs_s[tid] = obs[row * 128 + tid];
        __syncthreads();

        float s = -1e30f;
        if (tid < 100) {
            float a = attn_b[tid];
            #pragma unroll 4
            for (int k = 0; k < 128; k++) a += obs_s[k] * attn_W[k * 100 + tid];
            s = fmaxf(a, 0.f);
        }
        if (tid < 128) red[tid] = s;
        __syncthreads();
        for (int off = 64; off > 0; off >>= 1) {
            if (tid < off) red[tid] = fmaxf(red[tid], red[tid + off]);
            __syncthreads();
        }
        const float m = red[0];
        __syncthreads();
        const float e = (tid < 100) ? __expf(s - m) : 0.f;
        if (tid < 128) red[tid] = e;
        __syncthreads();
        for (int off = 64; off > 0; off >>= 1) {
            if (tid < off) red[tid] += red[tid + off];
            __syncthreads();
        }
        const float inv = __fdividef(1.f, red[0]);
        if (tid < 100) scores[row * 100 + tid] = e * inv;
    } else {
        // fragment reorder: 256 (tile,it) pairs total, 16 per block
        const int pb = blockIdx.x - 256;        // 0..15
        const int pair = pb * 16 + (tid >> 4);  // 0..255
        const int tile = pair >> 5;             // 0..7 (16-col tile)
        const int it   = pair & 31;             // K/32 chunk
        const int sub  = tid & 15;              // handles 4 lanes
        #pragma unroll
        for (int li = 0; li < 4; li++) {
            const int l = sub * 4 + li;
            const int c = tile * 16 + (l & 15);
            const int kbase = it * 32 + (l >> 4) * 8;
            half8 v;
            #pragma unroll
            for (int j = 0; j < 8; j++) v[j] = (_Float16)enc_W[(kbase + j) * 128 + c];
            *(half8*)(frag + (((long)(tile * 32 + it)) * 64 + l) * 8) = v;
        }
    }
}

// ---------------------------------------------------------------------------
// Kernel 2: persistent bidirectional LSTM (round-7 proven, 226us).
// Only change: out_feat stored f16.
// NOTE: launch_bounds(512,2) = 256-VGPR budget. (512,4) forces spill of the
// 96-VGPR B fragments -> 2.5 GB scratch traffic (round-6 regression).
// ---------------------------------------------------------------------------
__launch_bounds__(512, 2)
__global__ void lstm_kernel(const float* __restrict__ lane_features,
                            const float* __restrict__ embed_W,
                            const float* __restrict__ embed_b,
                            const float* __restrict__ Wih_f,
                            const float* __restrict__ Whh_f,
                            const float* __restrict__ b_f,
                            const float* __restrict__ Wih_b,
                            const float* __restrict__ Whh_b,
                            const float* __restrict__ b_b,
                            const float* __restrict__ h0,
                            const float* __restrict__ c0,
                            const int*   __restrict__ mask,
                            const float* __restrict__ scores,
                            _Float16* __restrict__ out_feat) {
    const int blk = blockIdx.x;
    const int d = blk >> 7;                     // 0 = fwd, 1 = bwd
    const int rowbase = (blk & 127) * ROWS_PB;
    const int tid = threadIdx.x;
    const int wave = tid >> 6;
    const int lane = tid & 63;
    const int lane16 = lane & 15;
    const int quad = lane >> 4;

    const float* Wih = d ? Wih_b : Wih_f;
    const float* Whh = d ? Whh_b : Whh_f;
    const float* bia = d ? b_b : b_f;

    __shared__ __attribute__((aligned(16))) _Float16 panel[2][ROWS_PB][SROW];
    __shared__ float att_s[ROWS_PB][100];

    // ---- Per-thread embed weights (columns cc..cc+3) ----
    const int erow = tid >> 4;                  // row this thread embeds
    const int cc = (tid & 15) * 4;
    float ew_r[4][4], eb_r[4];
    #pragma unroll
    for (int j = 0; j < 4; j++) {
        #pragma unroll
        for (int jj = 0; jj < 4; jj++) ew_r[j][jj] = embed_W[j * EMB + cc + jj];
    }
    #pragma unroll
    for (int jj = 0; jj < 4; jj++) eb_r[jj] = embed_b[cc + jj];

    // ---- att gather: att_s[r][t] = scores[mask[r]*100 + t] (one time) ----
    {
        const int r = tid >> 4, tcol = tid & 15;
        const int mr = mask[rowbase + r];
        for (int t = tcol; t < 100; t += 16) att_s[r][t] = scores[mr * 100 + t];
    }

    // ---- Preload B fragments (MFMA B layout), exp2 scales folded ----
    const int unitg = wave * 16 + lane16;
    half8 Bf[24];   // [ct][ki] -> 96 VGPRs
    #pragma unroll
    for (int ct = 0; ct < 4; ct++) {
        const float scale = (ct == 2) ? LOG2E2 : LOG2E;
        const int col = ct * 128 + unitg;
        #pragma unroll
        for (int ki = 0; ki < 6; ki++) {
            half8 b;
            #pragma unroll
            for (int j = 0; j < 8; j++) {
                const int kk = ki * 32 + quad * 8 + j;
                const float w = (kk < EMB) ? Wih[kk * GATES + col]
                                           : Whh[(kk - EMB) * GATES + col];
                b[j] = (_Float16)(w * scale);
            }
            Bf[ct * 6 + ki] = b;
        }
    }
    float bgate[4];
    #pragma unroll
    for (int ct = 0; ct < 4; ct++)
        bgate[ct] = bia[ct * 128 + unitg] * ((ct == 2) ? LOG2E2 : LOG2E);

    // ---- Per-lane state: 8 (row,unit) pairs in C-layout ----
    float cst[8], mx[8], as[8], h0s[8], hl[8];
    const float cinit = c0[d * 128 + unitg];
    #pragma unroll
    for (int p = 0; p < 8; p++) {
        cst[p] = cinit; mx[p] = -1e30f; as[p] = 0.f; h0s[p] = 0.f; hl[p] = 0.f;
    }

    // ---- Init panel[0]: h part ----
    for (int idx = tid; idx < ROWS_PB * HID; idx += 512) {
        const int r = idx >> 7, u = idx & 127;
        panel[0][r][EMB + u] = (_Float16)h0[d * 128 + u];
    }

    // ---- Init panel[0]: x for first step ----
    {
        const int t0 = d ? (TSTEPS - 1) : 0;
        const float4 fv = *(const float4*)(lane_features + (long)(rowbase + erow) * 600 + 200 + 4 * t0);
        #pragma unroll
        for (int jj = 0; jj < 4; jj++) {
            float e = eb_r[jj] + fv.x * ew_r[0][jj] + fv.y * ew_r[1][jj]
                               + fv.z * ew_r[2][jj] + fv.w * ew_r[3][jj];
            panel[0][erow][cc + jj] = (_Float16)fmaxf(e, 0.f);
        }
    }
    __syncthreads();

    // ================= main recurrence =================
    for (int s = 0; s < TSTEPS; s++) {
        const int p = s & 1;
        const int t = d ? (TSTEPS - 1 - s) : s;

        // prefetch next x features (VMEM latency overlaps MFMA below)
        float4 fv;
        if (s < TSTEPS - 1) {
            const int tn = d ? (TSTEPS - 2 - s) : (s + 1);
            fv = *(const float4*)(lane_features + (long)(rowbase + erow) * 600 + 200 + 4 * tn);
        }

        // attention weights (LDS broadcast reads)
        float aw[8];
        #pragma unroll
        for (int pp = 0; pp < 8; pp++) {
            const int row_local = (pp >> 2) * 16 + quad * 4 + (pp & 3);
            aw[pp] = att_s[row_local][t];
        }

        // accumulators pre-seeded with folded biases
        f32x4 acc[2][4];
        #pragma unroll
        for (int rt = 0; rt < 2; rt++)
            #pragma unroll
            for (int ct = 0; ct < 4; ct++) {
                const float bg = bgate[ct];
                acc[rt][ct] = (f32x4){bg, bg, bg, bg};
            }

        #pragma unroll
        for (int ki = 0; ki < 6; ki++) {
            const half8 a0 = *(const half8*)&panel[p][lane16][ki * 32 + quad * 8];
            const half8 a1 = *(const half8*)&panel[p][16 + lane16][ki * 32 + quad * 8];
            #pragma unroll
            for (int ct = 0; ct < 4; ct++) {
                acc[0][ct] = __builtin_amdgcn_mfma_f32_16x16x32_f16(a0, Bf[ct * 6 + ki], acc[0][ct], 0, 0, 0);
                acc[1][ct] = __builtin_amdgcn_mfma_f32_16x16x32_f16(a1, Bf[ct * 6 + ki], acc[1][ct], 0, 0, 0);
            }
        }

        // ---- cell update + online pooling (exp2-folded gates, proven r6/r7) ----
        #pragma unroll
        for (int rt = 0; rt < 2; rt++) {
            #pragma unroll
            for (int r = 0; r < 4; r++) {
                const int pp = rt * 4 + r;
                const int row_local = rt * 16 + quad * 4 + r;
                const float gi = acc[rt][0][r];
                const float gf = acc[rt][1][r];
                const float gg = fminf(acc[rt][2][r], 80.f);
                const float go = acc[rt][3][r];
                const float Ei = ex2(-gi);
                const float Ef = ex2(-gf);
                const float Eg = ex2(gg);
                const float Eo = ex2(-go);
                const float sf = rcpf(1.f + Ef);                       // sigmoid(f)
                const float r1 = rcpf((1.f + Ei) * (Eg + 1.f));
                const float cn = sf * cst[pp] + (Eg - 1.f) * r1;       // + sig(i)*tanh(g)
                const float Ec = ex2(fminf(cn * LOG2E2, 80.f));
                const float r2 = rcpf((1.f + Eo) * (Ec + 1.f));
                const float h = (Ec - 1.f) * r2;                       // sig(o)*tanh(c)
                cst[pp] = cn;
                hl[pp] = h;
                mx[pp] = fmaxf(mx[pp], h);
                as[pp] = fmaf(aw[pp], h, as[pp]);
                panel[1 - p][row_local][EMB + unitg] = (_Float16)h;
            }
        }
        if (s == 0) {
            #pragma unroll
            for (int pp = 0; pp < 8; pp++) h0s[pp] = hl[pp];
        }

        // ---- embed prefetched x into the other buffer ----
        if (s < TSTEPS - 1) {
            float e0 = eb_r[0] + fv.x * ew_r[0][0] + fv.y * ew_r[1][0] + fv.z * ew_r[2][0] + fv.w * ew_r[3][0];
            float e1 = eb_r[1] + fv.x * ew_r[0][1] + fv.y * ew_r[1][1] + fv.z * ew_r[2][1] + fv.w * ew_r[3][1];
            float e2 = eb_r[2] + fv.x * ew_r[0][2] + fv.y * ew_r[1][2] + fv.z * ew_r[2][2] + fv.w * ew_r[3][2];
            float e3 = eb_r[3] + fv.x * ew_r[0][3] + fv.y * ew_r[1][3] + fv.z * ew_r[2][3] + fv.w * ew_r[3][3];
            panel[1 - p][erow][cc]     = (_Float16)fmaxf(e0, 0.f);
            panel[1 - p][erow][cc + 1] = (_Float16)fmaxf(e1, 0.f);
            panel[1 - p][erow][cc + 2] = (_Float16)fmaxf(e2, 0.f);
            panel[1 - p][erow][cc + 3] = (_Float16)fmaxf(e3, 0.f);
        }
        __syncthreads();
    }

    // ---- pooled features: [front | back | max | attn], f16 ----
    #pragma unroll
    for (int pp = 0; pp < 8; pp++) {
        const int row_local = (pp >> 2) * 16 + quad * 4 + (pp & 3);
        const long ro = (long)(rowbase + row_local) * 1024;
        const int cu = d * 128 + unitg;
        const float fr = d ? hl[pp] : h0s[pp];
        const float bk = d ? h0s[pp] : hl[pp];
        out_feat[ro + cu]       = (_Float16)fr;
        out_feat[ro + 256 + cu] = (_Float16)bk;
        out_feat[ro + 512 + cu] = (_Float16)mx[pp];
        out_feat[ro + 768 + cu] = (_Float16)as[pp];
    }
}

// ---------------------------------------------------------------------------
// Kernel 3: out = relu(out_feat(4096x1024,f16) @ enc_W + enc_b)
// B from fragment-ordered table: each B load = contiguous 1KB per wave.
// ---------------------------------------------------------------------------
__launch_bounds__(256, 2)
__global__ void enc_kernel(const _Float16* __restrict__ out_feat,
                           const _Float16* __restrict__ frag,
                           const float* __restrict__ enc_b,
                           float* __restrict__ out) {
    const int rb = blockIdx.x * 16;
    const int tid = threadIdx.x;
    const int wave = tid >> 6;
    const int lane = tid & 63;
    const int lane16 = lane & 15;
    const int quad = lane >> 4;

    __shared__ __attribute__((aligned(16))) _Float16 A16[16][1032];

    // stage 16 rows x 1024 f16 of A (8 iters x 4KB)
    #pragma unroll
    for (int i = 0; i < 8; i++) {
        const int u = tid + i * 256;            // 0..2047, 16B chunks
        const int row = u >> 7, kc = u & 127;
        *(half8*)&A16[row][kc * 8] = *(const half8*)(out_feat + (long)(rb + row) * 1024 + kc * 8);
    }
    __syncthreads();

    const int col0 = wave * 32 + lane16;        // tile 2*wave; +16 -> tile 2*wave+1
    f32x4 acc0 = {0.f, 0.f, 0.f, 0.f}, acc1 = {0.f, 0.f, 0.f, 0.f};

    const _Float16* f0 = frag + ((long)(2 * wave) * 32 * 64) * 8 + lane * 8;
    const _Float16* f1 = frag + ((long)(2 * wave + 1) * 32 * 64) * 8 + lane * 8;

    #pragma unroll 4
    for (int it = 0; it < 32; it++) {
        const half8 a  = *(const half8*)&A16[lane16][it * 32 + quad * 8];
        const half8 b0 = *(const half8*)(f0 + (long)it * 64 * 8);
        const half8 b1 = *(const half8*)(f1 + (long)it * 64 * 8);
        acc0 = __builtin_amdgcn_mfma_f32_16x16x32_f16(a, b0, acc0, 0, 0, 0);
        acc1 = __builtin_amdgcn_mfma_f32_16x16x32_f16(a, b1, acc1, 0, 0, 0);
    }

    const float bb0 = enc_b[col0], bb1 = enc_b[col0 + 16];
    #pragma unroll
    for (int r = 0; r < 4; r++) {
        const int row = rb + quad * 4 + r;
        out[(long)row * 128 + col0]      = fmaxf(acc0[r] + bb0, 0.f);
        out[(long)row * 128 + col0 + 16] = fmaxf(acc1[r] + bb1, 0.f);
    }
}

// ---------------------------------------------------------------------------
extern "C" void kernel_launch(void* const* d_in, const int* in_sizes, int n_in,
                              void* d_out, int out_size, void* d_ws, size_t ws_size,
                              hipStream_t stream) {
    const float* lane_features = (const float*)d_in[0];
    const float* obs_encoding  = (const float*)d_in[1];
    const float* embed_W = (const float*)d_in[2];
    const float* embed_b = (const float*)d_in[3];
    const float* attn_W  = (const float*)d_in[4];
    const float* attn_b  = (const float*)d_in[5];
    const float* Wih_f   = (const float*)d_in[6];
    const float* Whh_f   = (const float*)d_in[7];
    const float* b_f     = (const float*)d_in[8];
    const float* Wih_b   = (const float*)d_in[9];
    const float* Whh_b   = (const float*)d_in[10];
    const float* b_b     = (const float*)d_in[11];
    const float* h0      = (const float*)d_in[12];
    const float* c0      = (const float*)d_in[13];
    const float* enc_W   = (const float*)d_in[14];
    const float* enc_b   = (const float*)d_in[15];
    const int*   mask    = (const int*)d_in[16];

    float*     scores   = (float*)d_ws;                            // 100 KB
    _Float16*  frag     = (_Float16*)((char*)d_ws + (128 << 10));  // 256 KB
    _Float16*  out_feat = (_Float16*)((char*)d_ws + (512 << 10));  // 8 MB
    float*     out      = (float*)d_out;                           // 4096*128 f32

    prep_kernel<<<272, 256, 0, stream>>>(obs_encoding, attn_W, attn_b, scores,
                                         enc_W, frag);
    lstm_kernel<<<256, 512, 0, stream>>>(lane_features, embed_W, embed_b,
                                         Wih_f, Whh_f, b_f, Wih_b, Whh_b, b_b,
                                         h0, c0, mask, scores, out_feat);
    enc_kernel<<<256, 256, 0, stream>>>(out_feat, frag, enc_b, out);
}

// Round 9
// 292.395 us; speedup vs baseline: 2.9684x; 1.0246x over previous
//
#include <hip/hip_runtime.h>
#include <hip/hip_bf16.h>

// Problem constants
#define MROWS 4096
#define TSTEPS 100
#define EMB 64
#define HID 128
#define GATES 512        // 4*HID
#define KTOT 192         // EMB + HID
#define ROWS_PB 32       // rows per block (one direction)
#define SROW 200         // padded A-panel row stride in f16 elems (400B, 16B aligned)
#define PSTR 520         // pooled-tile row stride in f16 elems (32x520x2 = 33280 B)

typedef _Float16 half8 __attribute__((ext_vector_type(8)));
typedef float f32x4 __attribute__((ext_vector_type(4)));

#define LOG2E  1.44269504f
#define LOG2E2 2.88539008f

__device__ __forceinline__ float rcpf(float x) { return __builtin_amdgcn_rcpf(x); }
__device__ __forceinline__ float ex2(float x) { return __builtin_amdgcn_exp2f(x); }

// ---------------------------------------------------------------------------
// Kernel 1 (merged prep):
//  blocks 0..255:  scores = softmax(relu(obs @ attn_W + attn_b)) (round-1 math)
//  blocks 256..271: enc_W (1024x128 f32) -> MFMA-B-fragment-ordered f16 table
//     frag[((tile*32 + it)*64 + lane)*8 + j] = enc_W[(it*32+(lane>>4)*8+j)*128
//                                                     + tile*16 + (lane&15)]
// ---------------------------------------------------------------------------
__global__ void prep_kernel(const float* __restrict__ obs,
                            const float* __restrict__ attn_W,
                            const float* __restrict__ attn_b,
                            float* __restrict__ scores,
                            const float* __restrict__ enc_W,
                            _Float16* __restrict__ frag) {
    const int tid = threadIdx.x;     // 256
    if (blockIdx.x < 256) {
        const int row = blockIdx.x;
        __shared__ float obs_s[128];
        __shared__ float red[128];

        if (tid < 128) obs_s[tid] = obs[row * 128 + tid];
        __syncthreads();

        float s = -1e30f;
        if (tid < 100) {
            float a = attn_b[tid];
            #pragma unroll 4
            for (int k = 0; k < 128; k++) a += obs_s[k] * attn_W[k * 100 + tid];
            s = fmaxf(a, 0.f);
        }
        if (tid < 128) red[tid] = s;
        __syncthreads();
        for (int off = 64; off > 0; off >>= 1) {
            if (tid < off) red[tid] = fmaxf(red[tid], red[tid + off]);
            __syncthreads();
        }
        const float m = red[0];
        __syncthreads();
        const float e = (tid < 100) ? __expf(s - m) : 0.f;
        if (tid < 128) red[tid] = e;
        __syncthreads();
        for (int off = 64; off > 0; off >>= 1) {
            if (tid < off) red[tid] += red[tid + off];
            __syncthreads();
        }
        const float inv = __fdividef(1.f, red[0]);
        if (tid < 100) scores[row * 100 + tid] = e * inv;
    } else {
        // fragment reorder: 256 (tile,it) pairs total, 16 per block
        const int pb = blockIdx.x - 256;        // 0..15
        const int pair = pb * 16 + (tid >> 4);  // 0..255
        const int tile = pair >> 5;             // 0..7 (16-col tile)
        const int it   = pair & 31;             // K/32 chunk
        const int sub  = tid & 15;              // handles 4 lanes
        #pragma unroll
        for (int li = 0; li < 4; li++) {
            const int l = sub * 4 + li;
            const int c = tile * 16 + (l & 15);
            const int kbase = it * 32 + (l >> 4) * 8;
            half8 v;
            #pragma unroll
            for (int j = 0; j < 8; j++) v[j] = (_Float16)enc_W[(kbase + j) * 128 + c];
            *(half8*)(frag + (((long)(tile * 32 + it)) * 64 + l) * 8) = v;
        }
    }
}

// ---------------------------------------------------------------------------
// Kernel 2: persistent bidirectional LSTM (round-7 proven, 226us)
// + fused partial encoder GEMM tail (this block's 512 K-columns),
//   partial written to pacc[d] (no atomics; fwd/bwd disjoint buffers).
// NOTE: launch_bounds(512,2) = 256-VGPR budget. (512,4) forces spill of the
// 96-VGPR B fragments -> 2.5 GB scratch traffic (round-6 regression).
// ---------------------------------------------------------------------------
__launch_bounds__(512, 2)
__global__ void lstm_kernel(const float* __restrict__ lane_features,
                            const float* __restrict__ embed_W,
                            const float* __restrict__ embed_b,
                            const float* __restrict__ Wih_f,
                            const float* __restrict__ Whh_f,
                            const float* __restrict__ b_f,
                            const float* __restrict__ Wih_b,
                            const float* __restrict__ Whh_b,
                            const float* __restrict__ b_b,
                            const float* __restrict__ h0,
                            const float* __restrict__ c0,
                            const int*   __restrict__ mask,
                            const float* __restrict__ scores,
                            const _Float16* __restrict__ frag,
                            float* __restrict__ pacc) {
    const int blk = blockIdx.x;
    const int d = blk >> 7;                     // 0 = fwd, 1 = bwd
    const int rowbase = (blk & 127) * ROWS_PB;
    const int tid = threadIdx.x;
    const int wave = tid >> 6;
    const int lane = tid & 63;
    const int lane16 = lane & 15;
    const int quad = lane >> 4;

    const float* Wih = d ? Wih_b : Wih_f;
    const float* Whh = d ? Whh_b : Whh_f;
    const float* bia = d ? b_b : b_f;

    // 38400-byte shared pool: panel (25600) + att_s (12800); reused at the
    // end as the 32x520-f16 pooled tile (33280 B) for the encoder tail.
    __shared__ __attribute__((aligned(16))) char smem[38400];
    auto panel = (_Float16 (*)[ROWS_PB][SROW])smem;          // panel[2][32][200]
    float (*att_s)[100] = (float (*)[100])(smem + 25600);    // att_s[32][100]
    _Float16* pool = (_Float16*)smem;                        // tail reuse

    // ---- Per-thread embed weights (columns cc..cc+3) ----
    const int erow = tid >> 4;                  // row this thread embeds
    const int cc = (tid & 15) * 4;
    float ew_r[4][4], eb_r[4];
    #pragma unroll
    for (int j = 0; j < 4; j++) {
        #pragma unroll
        for (int jj = 0; jj < 4; jj++) ew_r[j][jj] = embed_W[j * EMB + cc + jj];
    }
    #pragma unroll
    for (int jj = 0; jj < 4; jj++) eb_r[jj] = embed_b[cc + jj];

    // ---- att gather: att_s[r][t] = scores[mask[r]*100 + t] (one time) ----
    {
        const int r = tid >> 4, tcol = tid & 15;
        const int mr = mask[rowbase + r];
        for (int t = tcol; t < 100; t += 16) att_s[r][t] = scores[mr * 100 + t];
    }

    // ---- Preload B fragments (MFMA B layout), exp2 scales folded ----
    const int unitg = wave * 16 + lane16;
    half8 Bf[24];   // [ct][ki] -> 96 VGPRs
    #pragma unroll
    for (int ct = 0; ct < 4; ct++) {
        const float scale = (ct == 2) ? LOG2E2 : LOG2E;
        const int col = ct * 128 + unitg;
        #pragma unroll
        for (int ki = 0; ki < 6; ki++) {
            half8 b;
            #pragma unroll
            for (int j = 0; j < 8; j++) {
                const int kk = ki * 32 + quad * 8 + j;
                const float w = (kk < EMB) ? Wih[kk * GATES + col]
                                           : Whh[(kk - EMB) * GATES + col];
                b[j] = (_Float16)(w * scale);
            }
            Bf[ct * 6 + ki] = b;
        }
    }
    float bgate[4];
    #pragma unroll
    for (int ct = 0; ct < 4; ct++)
        bgate[ct] = bia[ct * 128 + unitg] * ((ct == 2) ? LOG2E2 : LOG2E);

    // ---- Per-lane state: 8 (row,unit) pairs in C-layout ----
    float cst[8], mx[8], as[8], h0s[8], hl[8];
    const float cinit = c0[d * 128 + unitg];
    #pragma unroll
    for (int p = 0; p < 8; p++) {
        cst[p] = cinit; mx[p] = -1e30f; as[p] = 0.f; h0s[p] = 0.f; hl[p] = 0.f;
    }

    // ---- Init panel[0]: h part ----
    for (int idx = tid; idx < ROWS_PB * HID; idx += 512) {
        const int r = idx >> 7, u = idx & 127;
        panel[0][r][EMB + u] = (_Float16)h0[d * 128 + u];
    }

    // ---- Init panel[0]: x for first step ----
    {
        const int t0 = d ? (TSTEPS - 1) : 0;
        const float4 fv = *(const float4*)(lane_features + (long)(rowbase + erow) * 600 + 200 + 4 * t0);
        #pragma unroll
        for (int jj = 0; jj < 4; jj++) {
            float e = eb_r[jj] + fv.x * ew_r[0][jj] + fv.y * ew_r[1][jj]
                               + fv.z * ew_r[2][jj] + fv.w * ew_r[3][jj];
            panel[0][erow][cc + jj] = (_Float16)fmaxf(e, 0.f);
        }
    }
    __syncthreads();

    // ================= main recurrence =================
    for (int s = 0; s < TSTEPS; s++) {
        const int p = s & 1;
        const int t = d ? (TSTEPS - 1 - s) : s;

        // prefetch next x features (VMEM latency overlaps MFMA below)
        float4 fv;
        if (s < TSTEPS - 1) {
            const int tn = d ? (TSTEPS - 2 - s) : (s + 1);
            fv = *(const float4*)(lane_features + (long)(rowbase + erow) * 600 + 200 + 4 * tn);
        }

        // attention weights (LDS broadcast reads)
        float aw[8];
        #pragma unroll
        for (int pp = 0; pp < 8; pp++) {
            const int row_local = (pp >> 2) * 16 + quad * 4 + (pp & 3);
            aw[pp] = att_s[row_local][t];
        }

        // accumulators pre-seeded with folded biases
        f32x4 acc[2][4];
        #pragma unroll
        for (int rt = 0; rt < 2; rt++)
            #pragma unroll
            for (int ct = 0; ct < 4; ct++) {
                const float bg = bgate[ct];
                acc[rt][ct] = (f32x4){bg, bg, bg, bg};
            }

        #pragma unroll
        for (int ki = 0; ki < 6; ki++) {
            const half8 a0 = *(const half8*)&panel[p][lane16][ki * 32 + quad * 8];
            const half8 a1 = *(const half8*)&panel[p][16 + lane16][ki * 32 + quad * 8];
            #pragma unroll
            for (int ct = 0; ct < 4; ct++) {
                acc[0][ct] = __builtin_amdgcn_mfma_f32_16x16x32_f16(a0, Bf[ct * 6 + ki], acc[0][ct], 0, 0, 0);
                acc[1][ct] = __builtin_amdgcn_mfma_f32_16x16x32_f16(a1, Bf[ct * 6 + ki], acc[1][ct], 0, 0, 0);
            }
        }

        // ---- cell update + online pooling (exp2-folded gates, proven r6/r7) ----
        #pragma unroll
        for (int rt = 0; rt < 2; rt++) {
            #pragma unroll
            for (int r = 0; r < 4; r++) {
                const int pp = rt * 4 + r;
                const int row_local = rt * 16 + quad * 4 + r;
                const float gi = acc[rt][0][r];
                const float gf = acc[rt][1][r];
                const float gg = fminf(acc[rt][2][r], 80.f);
                const float go = acc[rt][3][r];
                const float Ei = ex2(-gi);
                const float Ef = ex2(-gf);
                const float Eg = ex2(gg);
                const float Eo = ex2(-go);
                const float sf = rcpf(1.f + Ef);                       // sigmoid(f)
                const float r1 = rcpf((1.f + Ei) * (Eg + 1.f));
                const float cn = sf * cst[pp] + (Eg - 1.f) * r1;       // + sig(i)*tanh(g)
                const float Ec = ex2(fminf(cn * LOG2E2, 80.f));
                const float r2 = rcpf((1.f + Eo) * (Ec + 1.f));
                const float h = (Ec - 1.f) * r2;                       // sig(o)*tanh(c)
                cst[pp] = cn;
                hl[pp] = h;
                mx[pp] = fmaxf(mx[pp], h);
                as[pp] = fmaf(aw[pp], h, as[pp]);
                panel[1 - p][row_local][EMB + unitg] = (_Float16)h;
            }
        }
        if (s == 0) {
            #pragma unroll
            for (int pp = 0; pp < 8; pp++) h0s[pp] = hl[pp];
        }

        // ---- embed prefetched x into the other buffer ----
        if (s < TSTEPS - 1) {
            float e0 = eb_r[0] + fv.x * ew_r[0][0] + fv.y * ew_r[1][0] + fv.z * ew_r[2][0] + fv.w * ew_r[3][0];
            float e1 = eb_r[1] + fv.x * ew_r[0][1] + fv.y * ew_r[1][1] + fv.z * ew_r[2][1] + fv.w * ew_r[3][1];
            float e2 = eb_r[2] + fv.x * ew_r[0][2] + fv.y * ew_r[1][2] + fv.z * ew_r[2][2] + fv.w * ew_r[3][2];
            float e3 = eb_r[3] + fv.x * ew_r[0][3] + fv.y * ew_r[1][3] + fv.z * ew_r[2][3] + fv.w * ew_r[3][3];
            panel[1 - p][erow][cc]     = (_Float16)fmaxf(e0, 0.f);
            panel[1 - p][erow][cc + 1] = (_Float16)fmaxf(e1, 0.f);
            panel[1 - p][erow][cc + 2] = (_Float16)fmaxf(e2, 0.f);
            panel[1 - p][erow][cc + 3] = (_Float16)fmaxf(e3, 0.f);
        }
        __syncthreads();
    }

    // ===== fused encoder tail =====
    // Stage pooled tile in reused LDS: pool[row 0..31][kloc 0..511], kloc =
    // seg*128 + unit, segs = front|back|max|attn (this direction's halves).
    #pragma unroll
    for (int pp = 0; pp < 8; pp++) {
        const int row_local = (pp >> 2) * 16 + quad * 4 + (pp & 3);
        const float fr = d ? hl[pp] : h0s[pp];
        const float bk = d ? h0s[pp] : hl[pp];
        pool[row_local * PSTR + 0 * 128 + unitg] = (_Float16)fr;
        pool[row_local * PSTR + 1 * 128 + unitg] = (_Float16)bk;
        pool[row_local * PSTR + 2 * 128 + unitg] = (_Float16)mx[pp];
        pool[row_local * PSTR + 3 * 128 + unitg] = (_Float16)as[pp];
    }
    __syncthreads();

    // Partial GEMM: C[32 x 16cols(tile=wave)] += pool(32x512) @ enc_W slice.
    // Global K-chunk for local chunk lc=(seg,c): itg = seg*8 + d*4 + c.
    f32x4 cacc0 = {0.f, 0.f, 0.f, 0.f}, cacc1 = {0.f, 0.f, 0.f, 0.f};
    const _Float16* fbase = frag + ((long)wave * 32) * 64 * 8 + lane * 8;
    #pragma unroll
    for (int lc = 0; lc < 16; lc++) {
        const int seg = lc >> 2, c = lc & 3;
        const int itg = seg * 8 + d * 4 + c;
        const half8 b  = *(const half8*)(fbase + (long)itg * 64 * 8);
        const half8 a0 = *(const half8*)&pool[lane16 * PSTR + lc * 32 + quad * 8];
        const half8 a1 = *(const half8*)&pool[(16 + lane16) * PSTR + lc * 32 + quad * 8];
        cacc0 = __builtin_amdgcn_mfma_f32_16x16x32_f16(a0, b, cacc0, 0, 0, 0);
        cacc1 = __builtin_amdgcn_mfma_f32_16x16x32_f16(a1, b, cacc1, 0, 0, 0);
    }
    float* pacc_d = pacc + (long)d * MROWS * 128;
    #pragma unroll
    for (int r = 0; r < 4; r++) {
        pacc_d[(long)(rowbase + quad * 4 + r) * 128 + wave * 16 + lane16]      = cacc0[r];
        pacc_d[(long)(rowbase + 16 + quad * 4 + r) * 128 + wave * 16 + lane16] = cacc1[r];
    }
}

// ---------------------------------------------------------------------------
// Kernel 3: out = relu(paccA + paccB + enc_b)   (4096x128)
// ---------------------------------------------------------------------------
__global__ void final_kernel(const float* __restrict__ pacc,
                             const float* __restrict__ enc_b,
                             float* __restrict__ out) {
    const int idx = (blockIdx.x * 256 + threadIdx.x) * 4;   // 512 blocks
    const float4 a = *(const float4*)(pacc + idx);
    const float4 b = *(const float4*)(pacc + (long)MROWS * 128 + idx);
    const float4 bb = *(const float4*)(enc_b + (idx & 127));
    float4 o;
    o.x = fmaxf(a.x + b.x + bb.x, 0.f);
    o.y = fmaxf(a.y + b.y + bb.y, 0.f);
    o.z = fmaxf(a.z + b.z + bb.z, 0.f);
    o.w = fmaxf(a.w + b.w + bb.w, 0.f);
    *(float4*)(out + idx) = o;
}

// ---------------------------------------------------------------------------
extern "C" void kernel_launch(void* const* d_in, const int* in_sizes, int n_in,
                              void* d_out, int out_size, void* d_ws, size_t ws_size,
                              hipStream_t stream) {
    const float* lane_features = (const float*)d_in[0];
    const float* obs_encoding  = (const float*)d_in[1];
    const float* embed_W = (const float*)d_in[2];
    const float* embed_b = (const float*)d_in[3];
    const float* attn_W  = (const float*)d_in[4];
    const float* attn_b  = (const float*)d_in[5];
    const float* Wih_f   = (const float*)d_in[6];
    const float* Whh_f   = (const float*)d_in[7];
    const float* b_f     = (const float*)d_in[8];
    const float* Wih_b   = (const float*)d_in[9];
    const float* Whh_b   = (const float*)d_in[10];
    const float* b_b     = (const float*)d_in[11];
    const float* h0      = (const float*)d_in[12];
    const float* c0      = (const float*)d_in[13];
    const float* enc_W   = (const float*)d_in[14];
    const float* enc_b   = (const float*)d_in[15];
    const int*   mask    = (const int*)d_in[16];

    float*     scores = (float*)d_ws;                            // 100 KB
    _Float16*  frag   = (_Float16*)((char*)d_ws + (128 << 10));  // 256 KB
    float*     pacc   = (float*)((char*)d_ws + (512 << 10));     // 2 x 2 MB
    float*     out    = (float*)d_out;                           // 4096*128 f32

    prep_kernel<<<272, 256, 0, stream>>>(obs_encoding, attn_W, attn_b, scores,
                                         enc_W, frag);
    lstm_kernel<<<256, 512, 0, stream>>>(lane_features, embed_W, embed_b,
                                         Wih_f, Whh_f, b_f, Wih_b, Whh_b, b_b,
                                         h0, c0, mask, scores, frag, pacc);
    final_kernel<<<512, 256, 0, stream>>>(pacc, enc_b, out);
}

// Round 10
// 287.604 us; speedup vs baseline: 3.0178x; 1.0167x over previous
//
#include <hip/hip_runtime.h>
#include <hip/hip_bf16.h>

// Problem constants
#define MROWS 4096
#define TSTEPS 100
#define EMB 64
#define HID 128
#define GATES 512        // 4*HID
#define KTOT 192         // EMB + HID
#define ROWS_PB 32       // rows per block (one direction)
#define SROW 200         // padded A-panel row stride in f16 elems (400B, 16B aligned)
#define PSTR 520         // pooled-tile row stride in f16 elems (32x520x2 = 33280 B)

typedef _Float16 half8 __attribute__((ext_vector_type(8)));
typedef _Float16 half4v __attribute__((ext_vector_type(4)));
typedef float f32x4 __attribute__((ext_vector_type(4)));

#define LOG2E  1.44269504f
#define LOG2E2 2.88539008f

__device__ __forceinline__ float rcpf(float x) { return __builtin_amdgcn_rcpf(x); }
__device__ __forceinline__ float ex2(float x) { return __builtin_amdgcn_exp2f(x); }

// ---------------------------------------------------------------------------
// Kernel 1 (merged prep):
//  blocks 0..255:  scores = softmax(relu(obs @ attn_W + attn_b)) (round-1 math)
//  blocks 256..271: enc_W (1024x128 f32) -> MFMA-B-fragment-ordered f16 table
// ---------------------------------------------------------------------------
__global__ void prep_kernel(const float* __restrict__ obs,
                            const float* __restrict__ attn_W,
                            const float* __restrict__ attn_b,
                            float* __restrict__ scores,
                            const float* __restrict__ enc_W,
                            _Float16* __restrict__ frag) {
    const int tid = threadIdx.x;     // 256
    if (blockIdx.x < 256) {
        const int row = blockIdx.x;
        __shared__ float obs_s[128];
        __shared__ float red[128];

        if (tid < 128) obs_s[tid] = obs[row * 128 + tid];
        __syncthreads();

        float s = -1e30f;
        if (tid < 100) {
            float a = attn_b[tid];
            #pragma unroll 4
            for (int k = 0; k < 128; k++) a += obs_s[k] * attn_W[k * 100 + tid];
            s = fmaxf(a, 0.f);
        }
        if (tid < 128) red[tid] = s;
        __syncthreads();
        for (int off = 64; off > 0; off >>= 1) {
            if (tid < off) red[tid] = fmaxf(red[tid], red[tid + off]);
            __syncthreads();
        }
        const float m = red[0];
        __syncthreads();
        const float e = (tid < 100) ? __expf(s - m) : 0.f;
        if (tid < 128) red[tid] = e;
        __syncthreads();
        for (int off = 64; off > 0; off >>= 1) {
            if (tid < off) red[tid] += red[tid + off];
            __syncthreads();
        }
        const float inv = __fdividef(1.f, red[0]);
        if (tid < 100) scores[row * 100 + tid] = e * inv;
    } else {
        // fragment reorder: 256 (tile,it) pairs total, 16 per block
        const int pb = blockIdx.x - 256;        // 0..15
        const int pair = pb * 16 + (tid >> 4);  // 0..255
        const int tile = pair >> 5;             // 0..7 (16-col tile)
        const int it   = pair & 31;             // K/32 chunk
        const int sub  = tid & 15;              // handles 4 lanes
        #pragma unroll
        for (int li = 0; li < 4; li++) {
            const int l = sub * 4 + li;
            const int c = tile * 16 + (l & 15);
            const int kbase = it * 32 + (l >> 4) * 8;
            half8 v;
            #pragma unroll
            for (int j = 0; j < 8; j++) v[j] = (_Float16)enc_W[(kbase + j) * 128 + c];
            *(half8*)(frag + (((long)(tile * 32 + it)) * 64 + l) * 8) = v;
        }
    }
}

// ---------------------------------------------------------------------------
// Kernel 2: persistent bidirectional LSTM + fused partial encoder tail.
// 256 blocks x 512 thr, 32 rows/block, 1 block/CU, weights in VGPRs.
// Round-10: s-loop unrolled x2 (static LDS offsets), persistent bias accs,
// att_s transposed for b128 aw loads, running feature pointer.
// NOTE: launch_bounds(512,2) = 256-VGPR budget. (512,4) forces spill of the
// 96-VGPR B fragments -> 2.5 GB scratch traffic (round-6 regression).
// ---------------------------------------------------------------------------
__launch_bounds__(512, 2)
__global__ void lstm_kernel(const float* __restrict__ lane_features,
                            const float* __restrict__ embed_W,
                            const float* __restrict__ embed_b,
                            const float* __restrict__ Wih_f,
                            const float* __restrict__ Whh_f,
                            const float* __restrict__ b_f,
                            const float* __restrict__ Wih_b,
                            const float* __restrict__ Whh_b,
                            const float* __restrict__ b_b,
                            const float* __restrict__ h0,
                            const float* __restrict__ c0,
                            const int*   __restrict__ mask,
                            const float* __restrict__ scores,
                            const _Float16* __restrict__ frag,
                            float* __restrict__ pacc) {
    const int blk = blockIdx.x;
    const int d = blk >> 7;                     // 0 = fwd, 1 = bwd
    const int rowbase = (blk & 127) * ROWS_PB;
    const int tid = threadIdx.x;
    const int wave = tid >> 6;
    const int lane = tid & 63;
    const int lane16 = lane & 15;
    const int quad = lane >> 4;

    const float* Wih = d ? Wih_b : Wih_f;
    const float* Whh = d ? Whh_b : Whh_f;
    const float* bia = d ? b_b : b_f;

    // 38400-byte shared pool: panel (25600) + att_s (12800); reused at the
    // end as the 32x520-f16 pooled tile (33280 B) for the encoder tail.
    __shared__ __attribute__((aligned(16))) char smem[38400];
    auto panel = (_Float16 (*)[ROWS_PB][SROW])smem;          // panel[2][32][200]
    float (*att_s)[32] = (float (*)[32])(smem + 25600);      // att_s[100][32] (transposed)
    _Float16* pool = (_Float16*)smem;                        // tail reuse

    // ---- Per-thread embed weights (columns cc..cc+3) ----
    const int erow = tid >> 4;                  // row this thread embeds
    const int cc = (tid & 15) * 4;
    float ew_r[4][4], eb_r[4];
    #pragma unroll
    for (int j = 0; j < 4; j++) {
        #pragma unroll
        for (int jj = 0; jj < 4; jj++) ew_r[j][jj] = embed_W[j * EMB + cc + jj];
    }
    #pragma unroll
    for (int jj = 0; jj < 4; jj++) eb_r[jj] = embed_b[cc + jj];

    // ---- att gather (transposed): att_s[t][r] = scores[mask[r]*100 + t] ----
    {
        const int r = tid >> 4, tcol = tid & 15;
        const int mr = mask[rowbase + r];
        for (int t = tcol; t < 100; t += 16) att_s[t][r] = scores[mr * 100 + t];
    }

    // ---- Preload B fragments (MFMA B layout), exp2 scales folded ----
    const int unitg = wave * 16 + lane16;
    half8 Bf[24];   // [ct][ki] -> 96 VGPRs
    #pragma unroll
    for (int ct = 0; ct < 4; ct++) {
        const float scale = (ct == 2) ? LOG2E2 : LOG2E;
        const int col = ct * 128 + unitg;
        #pragma unroll
        for (int ki = 0; ki < 6; ki++) {
            half8 b;
            #pragma unroll
            for (int j = 0; j < 8; j++) {
                const int kk = ki * 32 + quad * 8 + j;
                const float w = (kk < EMB) ? Wih[kk * GATES + col]
                                           : Whh[(kk - EMB) * GATES + col];
                b[j] = (_Float16)(w * scale);
            }
            Bf[ct * 6 + ki] = b;
        }
    }
    // persistent bias accumulators (C operand of first MFMA in each chain)
    f32x4 biasacc[4];
    #pragma unroll
    for (int ct = 0; ct < 4; ct++) {
        const float bg = bia[ct * 128 + unitg] * ((ct == 2) ? LOG2E2 : LOG2E);
        biasacc[ct] = (f32x4){bg, bg, bg, bg};
    }

    // ---- Per-lane state: 8 (row,unit) pairs in C-layout ----
    float cst[8], mx[8], as[8], h0s[8], hl[8];
    const float cinit = c0[d * 128 + unitg];
    #pragma unroll
    for (int p = 0; p < 8; p++) {
        cst[p] = cinit; mx[p] = -1e30f; as[p] = 0.f; h0s[p] = 0.f; hl[p] = 0.f;
    }

    // ---- Init panel[0]: h part ----
    for (int idx = tid; idx < ROWS_PB * HID; idx += 512) {
        const int r = idx >> 7, u = idx & 127;
        panel[0][r][EMB + u] = (_Float16)h0[d * 128 + u];
    }

    // ---- Init panel[0]: x for first step ----
    {
        const int t0 = d ? (TSTEPS - 1) : 0;
        const float4 fv = *(const float4*)(lane_features + (long)(rowbase + erow) * 600 + 200 + 4 * t0);
        half4v hv;
        #pragma unroll
        for (int jj = 0; jj < 4; jj++) {
            float e = eb_r[jj] + fv.x * ew_r[0][jj] + fv.y * ew_r[1][jj]
                               + fv.z * ew_r[2][jj] + fv.w * ew_r[3][jj];
            hv[jj] = (_Float16)fmaxf(e, 0.f);
        }
        *(half4v*)&panel[0][erow][cc] = hv;
    }
    __syncthreads();

    // running feature pointer: first prefetch is step index 1 (t = d?98:1)
    const float* fptr = lane_features + (long)(rowbase + erow) * 600 + 200
                      + (d ? 4 * (TSTEPS - 2) : 4);
    const int fstep = d ? -4 : 4;

// One half-step: read panel[PB], write panel[1-PB]. SE = overall step index.
#define HALF_STEP(PB, SE)                                                      \
    {                                                                          \
        const int se = (SE);                                                   \
        const int t = d ? (TSTEPS - 1 - se) : se;                              \
        float4 fv;                                                             \
        if (se < TSTEPS - 1) { fv = *(const float4*)fptr; fptr += fstep; }     \
        const f32x4 awv0 = *(const f32x4*)&att_s[t][quad * 4];                 \
        const f32x4 awv1 = *(const f32x4*)&att_s[t][16 + quad * 4];            \
        f32x4 acc[2][4];                                                       \
        _Pragma("unroll")                                                      \
        for (int ki = 0; ki < 6; ki++) {                                       \
            const half8 a0 = *(const half8*)&panel[PB][lane16][ki * 32 + quad * 8];      \
            const half8 a1 = *(const half8*)&panel[PB][16 + lane16][ki * 32 + quad * 8]; \
            _Pragma("unroll")                                                  \
            for (int ct = 0; ct < 4; ct++) {                                   \
                if (ki == 0) {                                                 \
                    acc[0][ct] = __builtin_amdgcn_mfma_f32_16x16x32_f16(a0, Bf[ct * 6], biasacc[ct], 0, 0, 0); \
                    acc[1][ct] = __builtin_amdgcn_mfma_f32_16x16x32_f16(a1, Bf[ct * 6], biasacc[ct], 0, 0, 0); \
                } else {                                                       \
                    acc[0][ct] = __builtin_amdgcn_mfma_f32_16x16x32_f16(a0, Bf[ct * 6 + ki], acc[0][ct], 0, 0, 0); \
                    acc[1][ct] = __builtin_amdgcn_mfma_f32_16x16x32_f16(a1, Bf[ct * 6 + ki], acc[1][ct], 0, 0, 0); \
                }                                                              \
            }                                                                  \
        }                                                                      \
        _Pragma("unroll")                                                      \
        for (int rt = 0; rt < 2; rt++) {                                       \
            _Pragma("unroll")                                                  \
            for (int r = 0; r < 4; r++) {                                      \
                const int pp = rt * 4 + r;                                     \
                const int row_local = rt * 16 + quad * 4 + r;                  \
                const float gi = acc[rt][0][r];                                \
                const float gf = acc[rt][1][r];                                \
                const float gg = fminf(acc[rt][2][r], 80.f);                   \
                const float go = acc[rt][3][r];                                \
                const float Ei = ex2(-gi);                                     \
                const float Ef = ex2(-gf);                                     \
                const float Eg = ex2(gg);                                      \
                const float Eo = ex2(-go);                                     \
                const float sf = rcpf(1.f + Ef);                               \
                const float r1 = rcpf((1.f + Ei) * (Eg + 1.f));                \
                const float cn = sf * cst[pp] + (Eg - 1.f) * r1;               \
                const float Ec = ex2(fminf(cn * LOG2E2, 80.f));                \
                const float r2 = rcpf((1.f + Eo) * (Ec + 1.f));                \
                const float h = (Ec - 1.f) * r2;                               \
                cst[pp] = cn;                                                  \
                hl[pp] = h;                                                    \
                mx[pp] = fmaxf(mx[pp], h);                                     \
                as[pp] = fmaf((rt ? awv1 : awv0)[r], h, as[pp]);               \
                panel[1 - (PB)][row_local][EMB + unitg] = (_Float16)h;         \
            }                                                                  \
        }                                                                      \
        if (se == 0) {                                                         \
            _Pragma("unroll")                                                  \
            for (int pp = 0; pp < 8; pp++) h0s[pp] = hl[pp];                   \
        }                                                                      \
        if (se < TSTEPS - 1) {                                                 \
            half4v hv;                                                         \
            _Pragma("unroll")                                                  \
            for (int jj = 0; jj < 4; jj++) {                                   \
                float e = eb_r[jj] + fv.x * ew_r[0][jj] + fv.y * ew_r[1][jj]   \
                                   + fv.z * ew_r[2][jj] + fv.w * ew_r[3][jj];  \
                hv[jj] = (_Float16)fmaxf(e, 0.f);                              \
            }                                                                  \
            *(half4v*)&panel[1 - (PB)][erow][cc] = hv;                         \
        }                                                                      \
        __syncthreads();                                                       \
    }

    // ================= main recurrence (unrolled x2: p static) =============
    for (int s = 0; s < TSTEPS; s += 2) {
        HALF_STEP(0, s)
        HALF_STEP(1, s + 1)
    }
#undef HALF_STEP

    // ===== fused encoder tail =====
    // Stage pooled tile in reused LDS: pool[row 0..31][kloc 0..511], kloc =
    // seg*128 + unit, segs = front|back|max|attn (this direction's halves).
    #pragma unroll
    for (int pp = 0; pp < 8; pp++) {
        const int row_local = (pp >> 2) * 16 + quad * 4 + (pp & 3);
        const float fr = d ? hl[pp] : h0s[pp];
        const float bk = d ? h0s[pp] : hl[pp];
        pool[row_local * PSTR + 0 * 128 + unitg] = (_Float16)fr;
        pool[row_local * PSTR + 1 * 128 + unitg] = (_Float16)bk;
        pool[row_local * PSTR + 2 * 128 + unitg] = (_Float16)mx[pp];
        pool[row_local * PSTR + 3 * 128 + unitg] = (_Float16)as[pp];
    }
    __syncthreads();

    // Partial GEMM: C[32 x 16cols(tile=wave)] += pool(32x512) @ enc_W slice.
    // Global K-chunk for local chunk lc=(seg,c): itg = seg*8 + d*4 + c.
    f32x4 cacc0 = {0.f, 0.f, 0.f, 0.f}, cacc1 = {0.f, 0.f, 0.f, 0.f};
    const _Float16* fbase = frag + ((long)wave * 32) * 64 * 8 + lane * 8;
    #pragma unroll
    for (int lc = 0; lc < 16; lc++) {
        const int seg = lc >> 2, c = lc & 3;
        const int itg = seg * 8 + d * 4 + c;
        const half8 b  = *(const half8*)(fbase + (long)itg * 64 * 8);
        const half8 a0 = *(const half8*)&pool[lane16 * PSTR + lc * 32 + quad * 8];
        const half8 a1 = *(const half8*)&pool[(16 + lane16) * PSTR + lc * 32 + quad * 8];
        cacc0 = __builtin_amdgcn_mfma_f32_16x16x32_f16(a0, b, cacc0, 0, 0, 0);
        cacc1 = __builtin_amdgcn_mfma_f32_16x16x32_f16(a1, b, cacc1, 0, 0, 0);
    }
    float* pacc_d = pacc + (long)d * MROWS * 128;
    #pragma unroll
    for (int r = 0; r < 4; r++) {
        pacc_d[(long)(rowbase + quad * 4 + r) * 128 + wave * 16 + lane16]      = cacc0[r];
        pacc_d[(long)(rowbase + 16 + quad * 4 + r) * 128 + wave * 16 + lane16] = cacc1[r];
    }
}

// ---------------------------------------------------------------------------
// Kernel 3: out = relu(paccA + paccB + enc_b)   (4096x128)
// ---------------------------------------------------------------------------
__global__ void final_kernel(const float* __restrict__ pacc,
                             const float* __restrict__ enc_b,
                             float* __restrict__ out) {
    const int idx = (blockIdx.x * 256 + threadIdx.x) * 4;   // 512 blocks
    const float4 a = *(const float4*)(pacc + idx);
    const float4 b = *(const float4*)(pacc + (long)MROWS * 128 + idx);
    const float4 bb = *(const float4*)(enc_b + (idx & 127));
    float4 o;
    o.x = fmaxf(a.x + b.x + bb.x, 0.f);
    o.y = fmaxf(a.y + b.y + bb.y, 0.f);
    o.z = fmaxf(a.z + b.z + bb.z, 0.f);
    o.w = fmaxf(a.w + b.w + bb.w, 0.f);
    *(float4*)(out + idx) = o;
}

// ---------------------------------------------------------------------------
extern "C" void kernel_launch(void* const* d_in, const int* in_sizes, int n_in,
                              void* d_out, int out_size, void* d_ws, size_t ws_size,
                              hipStream_t stream) {
    const float* lane_features = (const float*)d_in[0];
    const float* obs_encoding  = (const float*)d_in[1];
    const float* embed_W = (const float*)d_in[2];
    const float* embed_b = (const float*)d_in[3];
    const float* attn_W  = (const float*)d_in[4];
    const float* attn_b  = (const float*)d_in[5];
    const float* Wih_f   = (const float*)d_in[6];
    const float* Whh_f   = (const float*)d_in[7];
    const float* b_f     = (const float*)d_in[8];
    const float* Wih_b   = (const float*)d_in[9];
    const float* Whh_b   = (const float*)d_in[10];
    const float* b_b     = (const float*)d_in[11];
    const float* h0      = (const float*)d_in[12];
    const float* c0      = (const float*)d_in[13];
    const float* enc_W   = (const float*)d_in[14];
    const float* enc_b   = (const float*)d_in[15];
    const int*   mask    = (const int*)d_in[16];

    float*     scores = (float*)d_ws;                            // 100 KB
    _Float16*  frag   = (_Float16*)((char*)d_ws + (128 << 10));  // 256 KB
    float*     pacc   = (float*)((char*)d_ws + (512 << 10));     // 2 x 2 MB
    float*     out    = (float*)d_out;                           // 4096*128 f32

    prep_kernel<<<272, 256, 0, stream>>>(obs_encoding, attn_W, attn_b, scores,
                                         enc_W, frag);
    lstm_kernel<<<256, 512, 0, stream>>>(lane_features, embed_W, embed_b,
                                         Wih_f, Whh_f, b_f, Wih_b, Whh_b, b_b,
                                         h0, c0, mask, scores, frag, pacc);
    final_kernel<<<512, 256, 0, stream>>>(pacc, enc_b, out);
}